// Round 4
// baseline (301.808 us; speedup 1.0000x reference)
//
#include <hip/hip_runtime.h>

// CLRNetIoULoss: pred/target (NL, 72) fp32 -> scalar fp32 loss.
// R4: single fused kernel. Coalesced pair-of-float4 loads (32B/lane),
// 9 partials/row staged in LDS (SoA, conflict-free), nonlinear iou per row,
// block reduce -> partial[blk]; last-block-done pattern does the final
// fixed-order fp64 reduction (deterministic) and writes the scalar.
// so = 2W*tp - D ; su = 2W*tp + D.

#define NR    72
#define NP2   9                // float4-PAIRS per row
#define BLOCK 256
#define RPB   256              // rows per block
#define P2PB  (RPB * NP2)      // 2304 pairs per array per block

__global__ __launch_bounds__(BLOCK, 8) void clrnet_fused(
    const float4* __restrict__ pred4,
    const float4* __restrict__ tgt4,
    float* __restrict__ partial,       // nblocks floats (d_ws)
    unsigned int* __restrict__ counter,// 1 uint (d_ws, zeroed per call)
    float* __restrict__ out,
    int nl, int nblocks, float inv_nl) {
  __shared__ float sd_[P2PB];   // per-pair D = sum|p-t| over both-valid
  __shared__ int   sc_[P2PB];   // per-pair tp | er<<8
  __shared__ float ws[BLOCK / 64];
  __shared__ int   is_last;

  const long long p2_total = (long long)nl * NP2;
  const long long base2 = (long long)blockIdx.x * P2PB;

  // ---- Phase 1: coalesced global (32B/lane) -> per-pair partials in LDS ----
#pragma unroll
  for (int k = 0; k < NP2; ++k) {
    const int iloc = k * BLOCK + threadIdx.x;          // 0..2303, linear
    const long long g2 = base2 + iloc;
    float d = 0.0f;
    int   c = 0;
    if (g2 < p2_total) {
      const float4* pp = pred4 + 2 * g2;
      const float4* tt = tgt4  + 2 * g2;
      float4 p0 = pp[0], p1 = pp[1];
      float4 t0 = tt[0], t1 = tt[1];
#pragma unroll
      for (int j = 0; j < 4; ++j) {
        float pv = (&p0.x)[j], tv = (&t0.x)[j];
        bool vp = (pv >= 0.0f) & (pv < 1.0f);
        bool vt = (tv >= 0.0f) & (tv < 1.0f);
        bool both = vp & vt;
        d += both ? fabsf(pv - tv) : 0.0f;
        c += (both ? 1 : 0) + ((vp != vt) ? 256 : 0);
      }
#pragma unroll
      for (int j = 0; j < 4; ++j) {
        float pv = (&p1.x)[j], tv = (&t1.x)[j];
        bool vp = (pv >= 0.0f) & (pv < 1.0f);
        bool vt = (tv >= 0.0f) & (tv < 1.0f);
        bool both = vp & vt;
        d += both ? fabsf(pv - tv) : 0.0f;
        c += (both ? 1 : 0) + ((vp != vt) ? 256 : 0);
      }
    }
    sd_[iloc] = d;     // linear in tid -> conflict-free
    sc_[iloc] = c;
  }
  __syncthreads();

  // ---- Phase 2: one thread per row, nonlinear part ----
  float loss = 0.0f;
  const long long row = (long long)blockIdx.x * RPB + threadIdx.x;
  if (row < nl) {
    float D = 0.0f;
    int   c = 0;
    const int rbase = threadIdx.x * NP2;   // stride 9 dwords: gcd(9,32)=1
#pragma unroll
    for (int j = 0; j < NP2; ++j) {
      D += sd_[rbase + j];
      c += sc_[rbase + j];
    }
    const int tp = c & 0xff;
    const int er = c >> 8;
    const float W2 = 2.0f * (15.0f / 800.0f);
    const float ftp = (float)tp;
    float so = W2 * ftp - D;
    float su = W2 * ftp + D;
    float iou = so / (su + 1e-9f);
    if (tp > er && er > 0) {
      iou *= (1.0f - (float)er / (ftp + 1e-9f));
    }
    loss = 1.0f - iou;
  }

  // ---- block reduce of loss ----
#pragma unroll
  for (int off = 32; off > 0; off >>= 1)
    loss += __shfl_down(loss, off, 64);

  const int lane = threadIdx.x & 63;
  const int wid  = threadIdx.x >> 6;
  if (lane == 0) ws[wid] = loss;
  __syncthreads();
  if (threadIdx.x == 0) {
    float s = 0.0f;
#pragma unroll
    for (int w = 0; w < BLOCK / 64; ++w) s += ws[w];
    partial[blockIdx.x] = s;
    __threadfence();                       // partial visible device-wide
    unsigned int old = atomicAdd(counter, 1u);
    is_last = (old == (unsigned int)(nblocks - 1)) ? 1 : 0;
  }
  __syncthreads();

  // ---- last block: fixed-order fp64 final reduction (deterministic) ----
  if (is_last) {
    double acc = 0.0;
    for (int i = threadIdx.x; i < nblocks; i += BLOCK)
      acc += (double)partial[i];
    __shared__ double sdd[BLOCK];
    sdd[threadIdx.x] = acc;
    __syncthreads();
#pragma unroll
    for (int s = BLOCK / 2; s > 0; s >>= 1) {
      if (threadIdx.x < s) sdd[threadIdx.x] += sdd[threadIdx.x + s];
      __syncthreads();
    }
    if (threadIdx.x == 0) {
      const double LOSS_WEIGHT = 1.0;
      out[0] = (float)(sdd[0] * (double)inv_nl * LOSS_WEIGHT);
    }
  }
}

extern "C" void kernel_launch(void* const* d_in, const int* in_sizes, int n_in,
                              void* d_out, int out_size, void* d_ws, size_t ws_size,
                              hipStream_t stream) {
  const float4* pred4 = (const float4*)d_in[0];
  const float4* tgt4  = (const float4*)d_in[1];
  float* out = (float*)d_out;

  const int nl = in_sizes[0] / NR;               // 1,000,000
  const int nblocks = (nl + RPB - 1) / RPB;      // 3907

  float* partial = (float*)d_ws;                          // nblocks floats
  unsigned int* counter = (unsigned int*)((char*)d_ws + 16384);

  hipMemsetAsync(counter, 0, sizeof(unsigned int), stream);
  clrnet_fused<<<nblocks, BLOCK, 0, stream>>>(pred4, tgt4, partial, counter,
                                              out, nl, nblocks,
                                              1.0f / (float)nl);
}

// Round 5
// 113.498 us; speedup vs baseline: 2.6592x; 2.6592x over previous
//
#include <hip/hip_runtime.h>

// CLRNetIoULoss: pred/target (NL, 72) fp32 -> scalar fp32 loss.
// R5: R3's streaming body (coalesced pair-of-float4, 9 LDS partials/row SoA,
// per-row nonlinear iou) + single-kernel finalize via ONE packed u64 atomic:
//   add (1<<52) + round(loss_block * 2^30)
// count in bits[52:63] (3907<4096), fixed-point sum in bits[0:51] (<2^51).
// Integer add is order-independent -> bitwise deterministic. No partials
// array, no __threadfence (R4's buffer_wbl2 storm), no second launch.

#define NR    72
#define NP2   9                // float4-PAIRS per row
#define BLOCK 256
#define RPB   256              // rows per block
#define P2PB  (RPB * NP2)      // 2304 pairs per array per block

#define CNT_SHIFT 52
#define SUM_MASK  ((1ULL << CNT_SHIFT) - 1ULL)
#define SCALE     1073741824.0   // 2^30

__global__ __launch_bounds__(BLOCK, 8) void clrnet_fused(
    const float4* __restrict__ pred4,
    const float4* __restrict__ tgt4,
    unsigned long long* __restrict__ acc,  // 1 u64 in d_ws, zeroed per call
    float* __restrict__ out,
    int nl, int nblocks, double inv_nl) {
  __shared__ float sd_[P2PB];   // per-pair D = sum|p-t| over both-valid
  __shared__ int   sc_[P2PB];   // per-pair tp | er<<8
  __shared__ float ws[BLOCK / 64];

  const long long p2_total = (long long)nl * NP2;
  const long long base2 = (long long)blockIdx.x * P2PB;

  // ---- Phase 1: coalesced global (32B/lane) -> per-pair partials in LDS ----
#pragma unroll
  for (int k = 0; k < NP2; ++k) {
    const int iloc = k * BLOCK + threadIdx.x;          // 0..2303, linear
    const long long g2 = base2 + iloc;
    float d = 0.0f;
    int   c = 0;
    if (g2 < p2_total) {
      const float4* pp = pred4 + 2 * g2;
      const float4* tt = tgt4  + 2 * g2;
      float4 p0 = pp[0], p1 = pp[1];
      float4 t0 = tt[0], t1 = tt[1];
#pragma unroll
      for (int j = 0; j < 4; ++j) {
        float pv = (&p0.x)[j], tv = (&t0.x)[j];
        bool vp = (pv >= 0.0f) & (pv < 1.0f);
        bool vt = (tv >= 0.0f) & (tv < 1.0f);
        bool both = vp & vt;
        d += both ? fabsf(pv - tv) : 0.0f;
        c += (both ? 1 : 0) + ((vp != vt) ? 256 : 0);
      }
#pragma unroll
      for (int j = 0; j < 4; ++j) {
        float pv = (&p1.x)[j], tv = (&t1.x)[j];
        bool vp = (pv >= 0.0f) & (pv < 1.0f);
        bool vt = (tv >= 0.0f) & (tv < 1.0f);
        bool both = vp & vt;
        d += both ? fabsf(pv - tv) : 0.0f;
        c += (both ? 1 : 0) + ((vp != vt) ? 256 : 0);
      }
    }
    sd_[iloc] = d;     // linear in tid -> conflict-free
    sc_[iloc] = c;
  }
  __syncthreads();

  // ---- Phase 2: one thread per row, nonlinear part ----
  float loss = 0.0f;
  const long long row = (long long)blockIdx.x * RPB + threadIdx.x;
  if (row < nl) {
    float D = 0.0f;
    int   c = 0;
    const int rbase = threadIdx.x * NP2;   // stride 9 dwords: gcd(9,32)=1
#pragma unroll
    for (int j = 0; j < NP2; ++j) {
      D += sd_[rbase + j];
      c += sc_[rbase + j];
    }
    const int tp = c & 0xff;
    const int er = c >> 8;
    const float W2 = 2.0f * (15.0f / 800.0f);
    const float ftp = (float)tp;
    float so = W2 * ftp - D;
    float su = W2 * ftp + D;
    float iou = so / (su + 1e-9f);
    if (tp > er && er > 0) {
      iou *= (1.0f - (float)er / (ftp + 1e-9f));
    }
    loss = 1.0f - iou;
  }

  // ---- block reduce of loss (fixed tree -> deterministic) ----
#pragma unroll
  for (int off = 32; off > 0; off >>= 1)
    loss += __shfl_down(loss, off, 64);

  const int lane = threadIdx.x & 63;
  const int wid  = threadIdx.x >> 6;
  if (lane == 0) ws[wid] = loss;
  __syncthreads();

  // ---- finalize: one packed u64 atomic per block ----
  if (threadIdx.x == 0) {
    float s = 0.0f;
#pragma unroll
    for (int w = 0; w < BLOCK / 64; ++w) s += ws[w];
    // quantize: loss_block in [0, 512) -> scaled < 2^39
    unsigned long long scaled =
        (unsigned long long)(long long)__double2ll_rn((double)s * SCALE);
    unsigned long long old =
        atomicAdd(acc, (1ULL << CNT_SHIFT) + scaled);
    if ((old >> CNT_SHIFT) == (unsigned long long)(nblocks - 1)) {
      // this add completed the sum; we hold the total in registers
      unsigned long long total = (old & SUM_MASK) + scaled;
      const double LOSS_WEIGHT = 1.0;
      out[0] = (float)((double)total * (1.0 / SCALE) * inv_nl * LOSS_WEIGHT);
    }
  }
}

extern "C" void kernel_launch(void* const* d_in, const int* in_sizes, int n_in,
                              void* d_out, int out_size, void* d_ws, size_t ws_size,
                              hipStream_t stream) {
  const float4* pred4 = (const float4*)d_in[0];
  const float4* tgt4  = (const float4*)d_in[1];
  float* out = (float*)d_out;

  const int nl = in_sizes[0] / NR;               // 1,000,000
  const int nblocks = (nl + RPB - 1) / RPB;      // 3907

  unsigned long long* acc = (unsigned long long*)d_ws;

  hipMemsetAsync(acc, 0, sizeof(unsigned long long), stream);
  clrnet_fused<<<nblocks, BLOCK, 0, stream>>>(pred4, tgt4, acc, out,
                                              nl, nblocks,
                                              1.0 / (double)nl);
}

// Round 6
// 107.615 us; speedup vs baseline: 2.8045x; 1.0547x over previous
//
#include <hip/hip_runtime.h>

// CLRNetIoULoss: pred/target (NL, 72) fp32 -> scalar fp32 loss.
// R6 = R3 (best: 107.6us) + u32 BYTE-offset addressing (span 288MB < 4GB, so
// SGPR-base + 32-bit voffset loads, no v_*_u64 address chains) + uniform
// fast path (per-iter bounds guard only in the single tail block).
// Structure: coalesced pair-of-float4 (32B/lane), 9 partials/row in LDS SoA,
// per-row nonlinear iou, block reduce -> partial[blk]; tiny fp64 finish kernel.
// so = 2W*tp - D ; su = 2W*tp + D.

#define NR    72
#define NP2   9                // float4-PAIRS per row
#define BLOCK 256
#define RPB   256              // rows per block
#define P2PB  (RPB * NP2)      // 2304 pairs per array per block

__device__ __forceinline__ void accum_pair(const char* pred, const char* tgt,
                                           unsigned off, float& d, int& c) {
  float4 p0 = *(const float4*)(pred + off);
  float4 p1 = *(const float4*)(pred + off + 16);
  float4 t0 = *(const float4*)(tgt + off);
  float4 t1 = *(const float4*)(tgt + off + 16);
#pragma unroll
  for (int j = 0; j < 4; ++j) {
    float pv = (&p0.x)[j], tv = (&t0.x)[j];
    bool vp = (pv >= 0.0f) & (pv < 1.0f);
    bool vt = (tv >= 0.0f) & (tv < 1.0f);
    bool both = vp & vt;
    d += both ? fabsf(pv - tv) : 0.0f;
    c += (both ? 1 : 0) + ((vp != vt) ? 256 : 0);
  }
#pragma unroll
  for (int j = 0; j < 4; ++j) {
    float pv = (&p1.x)[j], tv = (&t1.x)[j];
    bool vp = (pv >= 0.0f) & (pv < 1.0f);
    bool vt = (tv >= 0.0f) & (tv < 1.0f);
    bool both = vp & vt;
    d += both ? fabsf(pv - tv) : 0.0f;
    c += (both ? 1 : 0) + ((vp != vt) ? 256 : 0);
  }
}

__global__ __launch_bounds__(BLOCK, 8) void clrnet_iou_rows(
    const char* __restrict__ pred,
    const char* __restrict__ tgt,
    float* __restrict__ partial,   // one float per block
    int nl) {
  __shared__ float sd_[P2PB];   // per-pair D = sum|p-t| over both-valid
  __shared__ int   sc_[P2PB];   // per-pair tp | er<<8
  __shared__ float ws[BLOCK / 64];

  const unsigned base_b = (unsigned)blockIdx.x * (P2PB * 32u); // byte offset
  const bool full = ((int)blockIdx.x != (int)gridDim.x - 1);   // uniform

  // ---- Phase 1: coalesced global (32B/lane) -> per-pair partials in LDS ----
  if (full) {
#pragma unroll
    for (int k = 0; k < NP2; ++k) {
      const int iloc = k * BLOCK + threadIdx.x;        // 0..2303, linear
      const unsigned off = base_b + (unsigned)iloc * 32u;
      float d = 0.0f;
      int   c = 0;
      accum_pair(pred, tgt, off, d, c);
      sd_[iloc] = d;     // linear in tid -> conflict-free
      sc_[iloc] = c;
    }
  } else {
    const int tail_pairs = nl * NP2 - (int)blockIdx.x * P2PB;  // 576 here
#pragma unroll
    for (int k = 0; k < NP2; ++k) {
      const int iloc = k * BLOCK + threadIdx.x;
      float d = 0.0f;
      int   c = 0;
      if (iloc < tail_pairs) {
        const unsigned off = base_b + (unsigned)iloc * 32u;
        accum_pair(pred, tgt, off, d, c);
      }
      sd_[iloc] = d;
      sc_[iloc] = c;
    }
  }
  __syncthreads();

  // ---- Phase 2: one thread per row, nonlinear part ----
  float loss = 0.0f;
  const int row = (int)blockIdx.x * RPB + (int)threadIdx.x;
  if (row < nl) {
    float D = 0.0f;
    int   c = 0;
    const int rbase = threadIdx.x * NP2;   // stride 9 dwords: gcd(9,32)=1
#pragma unroll
    for (int j = 0; j < NP2; ++j) {
      D += sd_[rbase + j];
      c += sc_[rbase + j];
    }
    const int tp = c & 0xff;
    const int er = c >> 8;
    const float W2 = 2.0f * (15.0f / 800.0f);
    const float ftp = (float)tp;
    float so = W2 * ftp - D;
    float su = W2 * ftp + D;
    float iou = so / (su + 1e-9f);
    if (tp > er && er > 0) {
      iou *= (1.0f - (float)er / (ftp + 1e-9f));
    }
    loss = 1.0f - iou;
  }

  // ---- block reduce of loss ----
#pragma unroll
  for (int off = 32; off > 0; off >>= 1)
    loss += __shfl_down(loss, off, 64);

  const int lane = threadIdx.x & 63;
  const int wid  = threadIdx.x >> 6;
  if (lane == 0) ws[wid] = loss;
  __syncthreads();
  if (threadIdx.x == 0) {
    float s = 0.0f;
#pragma unroll
    for (int w = 0; w < BLOCK / 64; ++w) s += ws[w];
    partial[blockIdx.x] = s;
  }
}

__global__ __launch_bounds__(256) void clrnet_iou_finish(
    const float* __restrict__ partial, int nparts, float* __restrict__ out,
    float inv_nl) {
  // single block; fp64 accumulation for deterministic, accurate final sum
  double acc = 0.0;
  for (int i = threadIdx.x; i < nparts; i += 256)
    acc += (double)partial[i];

  __shared__ double sd[256];
  sd[threadIdx.x] = acc;
  __syncthreads();
#pragma unroll
  for (int s = 128; s > 0; s >>= 1) {
    if (threadIdx.x < s) sd[threadIdx.x] += sd[threadIdx.x + s];
    __syncthreads();
  }
  if (threadIdx.x == 0) {
    const double LOSS_WEIGHT = 1.0;
    out[0] = (float)(sd[0] * (double)inv_nl * LOSS_WEIGHT);
  }
}

extern "C" void kernel_launch(void* const* d_in, const int* in_sizes, int n_in,
                              void* d_out, int out_size, void* d_ws, size_t ws_size,
                              hipStream_t stream) {
  const char* pred = (const char*)d_in[0];
  const char* tgt  = (const char*)d_in[1];
  float* out = (float*)d_out;

  const int nl = in_sizes[0] / NR;               // 1,000,000
  const int nblocks = (nl + RPB - 1) / RPB;      // 3907

  float* partial = (float*)d_ws;                 // nblocks floats of scratch

  clrnet_iou_rows<<<nblocks, BLOCK, 0, stream>>>(pred, tgt, partial, nl);
  clrnet_iou_finish<<<1, 256, 0, stream>>>(partial, nblocks, out,
                                           1.0f / (float)nl);
}